// Round 3
// baseline (295.827 us; speedup 1.0000x reference)
//
#include <hip/hip_runtime.h>

#define NT 256

// Tile status word: bits[31:30] = flag, bits[29:0] = value.
// Max total = 2e6 * 4 = 8e6 < 2^30, fits.
#define FLAG_INV 0u   // not yet published (matches zero-init)
#define FLAG_AGG 1u   // aggregate (block-local total) available
#define FLAG_PRE 2u   // inclusive prefix available

// Kernel 0: zero tile-status array + tile counter (workspace may be poisoned,
// and graph replay must re-zero every iteration).
__global__ __launch_bounds__(NT) void init_status(unsigned* __restrict__ status, int nb) {
    int i = blockIdx.x * NT + threadIdx.x;
    if (i < nb + 1) status[i] = 0u;   // [0] = tile counter, [1..nb] = status
}

// Kernel 1: fused scan (decoupled lookback) + compute + ordered compaction.
// SAFETY: tile id comes from a global atomic counter (rocPRIM ordered_block_id
// pattern) so tile order == scheduling order -> lookback forward progress is
// guaranteed regardless of HW dispatch order across XCDs (guide §6 G16).
__global__ __launch_bounds__(NT) void fused_kernel(const float* __restrict__ xss,
                                                   const int* __restrict__ seq,
                                                   const float* __restrict__ Wcob,
                                                   const float* __restrict__ Wreg,
                                                   unsigned* __restrict__ ws,
                                                   float* __restrict__ out,
                                                   int n) {
    unsigned* counter = ws;        // one word
    unsigned* status  = ws + 1;    // nb words

    __shared__ unsigned wtot[4];
    __shared__ unsigned s_bid;           // virtual (ordered) tile id
    __shared__ unsigned s_excl;          // block-exclusive global offset
    __shared__ float outbuf[NT * 4];     // staging for coalesced output

    const int tid  = threadIdx.x;
    const int lane = tid & 63;
    const int wave = tid >> 6;

    if (tid == 0) s_bid = atomicAdd(counter, 1u);   // device-scope by default
    __syncthreads();
    const int bid = (int)s_bid;
    const int gid = bid * NT + tid;

    unsigned L = (gid < n) ? (unsigned)seq[gid] : 0u;

    // Issue the 80B xss load EARLY: its HBM latency hides under the
    // scan + lookback (loads target private VGPRs, barriers don't drain vmcnt).
    const int cgid = (gid < n) ? gid : (n - 1);   // clamp: avoid OOB, data unused when L==0
    const float* p = xss + (size_t)cgid * 20;
    float4 v0 = *(const float4*)(p + 0);
    float4 v1 = *(const float4*)(p + 4);
    float4 v2 = *(const float4*)(p + 8);
    float4 v3 = *(const float4*)(p + 12);
    float4 v4 = *(const float4*)(p + 16);

    // ---- block-wide exclusive scan of L (shfl intra-wave, LDS cross-wave) ----
    unsigned v = L;
    #pragma unroll
    for (int off = 1; off < 64; off <<= 1) {
        unsigned t = __shfl_up(v, off);
        if (lane >= off) v += t;
    }
    if (lane == 63) wtot[wave] = v;
    __syncthreads();
    unsigned woff = 0;
    #pragma unroll
    for (int w = 0; w < 4; w++) woff += (w < wave) ? wtot[w] : 0u;
    const unsigned total      = wtot[0] + wtot[1] + wtot[2] + wtot[3];
    const unsigned excl_local = woff + v - L;

    // ---- publish aggregate IMMEDIATELY (before any waiting) ----
    // flag+value packed in one 32-bit word => one relaxed agent-scope atomic
    // is self-consistent; no acquire/release pairing needed.
    if (tid == 0) {
        unsigned word = ((bid == 0) ? (FLAG_PRE << 30) : (FLAG_AGG << 30)) | total;
        __hip_atomic_store(&status[bid], word, __ATOMIC_RELAXED, __HIP_MEMORY_SCOPE_AGENT);
        if (bid == 0) s_excl = 0u;
    }

    // ---- wave-parallel decoupled lookback (wave 0 only) ----
    if (bid > 0 && tid < 64) {
        unsigned run = 0;
        int j = bid;                       // window is [j-64, j-1], lane -> j-64+lane
        for (;;) {
            int idx = j - 64 + tid;
            unsigned s = (idx >= 0)
                ? __hip_atomic_load(&status[idx], __ATOMIC_RELAXED, __HIP_MEMORY_SCOPE_AGENT)
                : (FLAG_PRE << 30);        // synthetic prefix of 0 below tile 0
            unsigned flag = s >> 30;
            unsigned long long bal_inv = __ballot(flag == FLAG_INV);
            unsigned long long bal_pre = __ballot(flag == FLAG_PRE);
            int hi = (bal_inv == 0ull) ? -1 : (63 - __clzll(bal_inv));
            int hp = (bal_pre == 0ull) ? -1 : (63 - __clzll(bal_pre));
            if (hp > hi) {
                // closest prefix with no gaps above it: sum lanes >= hp and stop
                unsigned c = (tid >= hp) ? (s & 0x3FFFFFFFu) : 0u;
                #pragma unroll
                for (int off = 32; off > 0; off >>= 1) c += __shfl_down(c, off);
                run += __shfl(c, 0);
                break;
            } else if (hi < 0) {
                // whole window is aggregates: consume and step back
                unsigned c = s & 0x3FFFFFFFu;
                #pragma unroll
                for (int off = 32; off > 0; off >>= 1) c += __shfl_down(c, off);
                run += __shfl(c, 0);
                j -= 64;
            } else {
                __builtin_amdgcn_s_sleep(1);  // back off while predecessor publishes
            }
        }
        if (tid == 0) {
            __hip_atomic_store(&status[bid],
                               (FLAG_PRE << 30) | ((run + total) & 0x3FFFFFFFu),
                               __ATOMIC_RELAXED, __HIP_MEMORY_SCOPE_AGENT);
            s_excl = run;
        }
    }

    // ---- per-element compute (all waves; wave 0 after its lookback) ----
    float wc[16], wr[16];                  // uniform addresses -> scalar loads
    #pragma unroll
    for (int i = 0; i < 16; i++) { wc[i] = Wcob[i]; wr[i] = Wreg[i]; }

    float x[20];
    x[0]=v0.x;  x[1]=v0.y;  x[2]=v0.z;  x[3]=v0.w;
    x[4]=v1.x;  x[5]=v1.y;  x[6]=v1.z;  x[7]=v1.w;
    x[8]=v2.x;  x[9]=v2.y;  x[10]=v2.z; x[11]=v2.w;
    x[12]=v3.x; x[13]=v3.y; x[14]=v3.z; x[15]=v3.w;
    x[16]=v4.x; x[17]=v4.y; x[18]=v4.z; x[19]=v4.w;

    // bs[s][c] = sum_f fs[s][f] * Wcob[c][f]
    float bs[4][4];
    #pragma unroll
    for (int s = 0; s < 4; s++) {
        #pragma unroll
        for (int c = 0; c < 4; c++) {
            float acc = 0.f;
            #pragma unroll
            for (int f = 0; f < 4; f++) acc += x[s * 5 + 1 + f] * wc[c * 4 + f];
            bs[s][c] = acc;
        }
    }

    // context[c] = sum_{s<L} bs[s][c] * scale[s]
    float ctx[4] = {0.f, 0.f, 0.f, 0.f};
    #pragma unroll
    for (int s = 0; s < 4; s++) {
        float m = (s < (int)L) ? x[s * 5] : 0.f;
        #pragma unroll
        for (int c = 0; c < 4; c++) ctx[c] += bs[s][c] * m;
    }

    // ys[m] = sum_c context[c] * Wreg[m][c]
    float ys[4];
    #pragma unroll
    for (int m = 0; m < 4; m++) {
        float acc = 0.f;
        #pragma unroll
        for (int c = 0; c < 4; c++) acc += ctx[c] * wr[m * 4 + c];
        ys[m] = acc;
    }

    // projs[s] = sum_m bs[s][m] * ys[m]; stage into LDS at the block-local slot.
    #pragma unroll
    for (int s = 0; s < 4; s++) {
        if (s < (int)L) {
            float acc = 0.f;
            #pragma unroll
            for (int m = 0; m < 4; m++) acc += bs[s][m] * ys[m];
            outbuf[excl_local + s] = acc;
        }
    }

    // One barrier covers both: s_excl written (wave-0 lane 0) and outbuf staged.
    __syncthreads();
    const unsigned base = s_excl;
    for (unsigned i = tid; i < total; i += NT)
        out[base + i] = outbuf[i];
}

extern "C" void kernel_launch(void* const* d_in, const int* in_sizes, int n_in,
                              void* d_out, int out_size, void* d_ws, size_t ws_size,
                              hipStream_t stream) {
    const float* xss  = (const float*)d_in[0];
    const int*   seq  = (const int*)d_in[1];
    const float* Wcob = (const float*)d_in[2];
    const float* Wreg = (const float*)d_in[3];
    float* out = (float*)d_out;

    int n  = in_sizes[1];            // B = 2,000,000
    int nb = (n + NT - 1) / NT;      // 7813 tiles

    unsigned* ws = (unsigned*)d_ws;  // [0]=tile counter, [1..nb]=status (~31 KB)

    int ib = (nb + 1 + NT - 1) / NT;
    init_status<<<ib, NT, 0, stream>>>(ws, nb);
    fused_kernel<<<nb, NT, 0, stream>>>(xss, seq, Wcob, Wreg, ws, out, n);
}

// Round 4
// 271.384 us; speedup vs baseline: 1.0901x; 1.0901x over previous
//
#include <hip/hip_runtime.h>

#define NT 256
#define EPT 4                 // elements per thread
#define BLK_ELEMS (NT * EPT)  // 1024 elements per block

// K1: per-block (1024-element) sum of seq_lengths.
__global__ __launch_bounds__(NT) void tile_sum_kernel(const int* __restrict__ seq,
                                                      unsigned* __restrict__ blockTotal,
                                                      int n) {
    __shared__ unsigned wsum[4];
    const int tid = threadIdx.x, lane = tid & 63, wave = tid >> 6;
    const int base = blockIdx.x * BLK_ELEMS + tid * EPT;
    unsigned v = 0;
    if (base + EPT <= n) {
        int4 q = *(const int4*)(seq + base);
        v = (unsigned)(q.x + q.y + q.z + q.w);
    } else {
        for (int e = 0; e < EPT; e++)
            if (base + e < n) v += (unsigned)seq[base + e];
    }
    #pragma unroll
    for (int off = 32; off > 0; off >>= 1) v += __shfl_down(v, off);
    if (lane == 0) wsum[wave] = v;
    __syncthreads();
    if (tid == 0) blockTotal[blockIdx.x] = wsum[0] + wsum[1] + wsum[2] + wsum[3];
}

// K2: each block redundantly reduces blockTotal[0..bid) for its global prefix
// (L2-broadcast, ~7.6KB max), block-scans its own 1024 seq values, then does
// the per-element compute + ordered compacted stores. No atomics, no waiting.
__global__ __launch_bounds__(NT) void main_kernel(const float* __restrict__ xss,
                                                  const int* __restrict__ seq,
                                                  const float* __restrict__ Wcob,
                                                  const float* __restrict__ Wreg,
                                                  const unsigned* __restrict__ blockTotal,
                                                  float* __restrict__ out,
                                                  int n) {
    __shared__ unsigned wred[4];  // cross-wave partials of the prefix reduce
    __shared__ unsigned wtot[4];  // cross-wave inclusive totals of the scan
    const int tid = threadIdx.x, lane = tid & 63, wave = tid >> 6;
    const int bid = blockIdx.x;
    const int base = bid * BLK_ELEMS + tid * EPT;

    // ---- this thread's 4 seq values (int4 when fully in-range) ----
    int l[EPT];
    if (base + EPT <= n) {
        int4 q = *(const int4*)(seq + base);
        l[0] = q.x; l[1] = q.y; l[2] = q.z; l[3] = q.w;
    } else {
        #pragma unroll
        for (int e = 0; e < EPT; e++) l[e] = (base + e < n) ? seq[base + e] : 0;
    }
    const unsigned tsum = (unsigned)(l[0] + l[1] + l[2] + l[3]);

    // ---- global prefix: reduce blockTotal[0..bid) (<=8 strided L2 loads) ----
    unsigned acc = 0;
    for (int i = tid; i < bid; i += NT) acc += blockTotal[i];
    unsigned r = acc;
    #pragma unroll
    for (int off = 32; off > 0; off >>= 1) r += __shfl_down(r, off);
    if (lane == 0) wred[wave] = r;

    // ---- block-wide exclusive scan over thread sums (same barrier window) ----
    unsigned v = tsum;
    #pragma unroll
    for (int off = 1; off < 64; off <<= 1) {
        unsigned t = __shfl_up(v, off);
        if (lane >= off) v += t;
    }
    if (lane == 63) wtot[wave] = v;
    __syncthreads();
    const unsigned prefix = wred[0] + wred[1] + wred[2] + wred[3];
    unsigned woff = 0;
    #pragma unroll
    for (int w = 0; w < 4; w++) woff += (w < wave) ? wtot[w] : 0u;
    unsigned o = prefix + woff + (v - tsum);  // this thread's first output slot

    // ---- uniform-address weight loads -> scalar loads ----
    float wc[16], wr[16];
    #pragma unroll
    for (int i = 0; i < 16; i++) { wc[i] = Wcob[i]; wr[i] = Wreg[i]; }

    // ---- per-element compute; thread's 4 elements are CONSECUTIVE so its
    //      outputs are consecutive too; consecutive threads adjacent. ----
    #pragma unroll
    for (int e = 0; e < EPT; e++) {
        const int gid = base + e;
        const int L = l[e];
        if (gid < n && L > 0) {
            const float* p = xss + (size_t)gid * 20;
            float4 v0 = *(const float4*)(p + 0);
            float4 v1 = *(const float4*)(p + 4);
            float4 v2 = *(const float4*)(p + 8);
            float4 v3 = *(const float4*)(p + 12);
            float4 v4 = *(const float4*)(p + 16);
            float x[20];
            x[0]=v0.x;  x[1]=v0.y;  x[2]=v0.z;  x[3]=v0.w;
            x[4]=v1.x;  x[5]=v1.y;  x[6]=v1.z;  x[7]=v1.w;
            x[8]=v2.x;  x[9]=v2.y;  x[10]=v2.z; x[11]=v2.w;
            x[12]=v3.x; x[13]=v3.y; x[14]=v3.z; x[15]=v3.w;
            x[16]=v4.x; x[17]=v4.y; x[18]=v4.z; x[19]=v4.w;

            // bs[s][c] = sum_f fs[s][f] * Wcob[c][f]
            float bs[4][4];
            #pragma unroll
            for (int s = 0; s < 4; s++) {
                #pragma unroll
                for (int c = 0; c < 4; c++) {
                    float a = 0.f;
                    #pragma unroll
                    for (int f = 0; f < 4; f++) a += x[s * 5 + 1 + f] * wc[c * 4 + f];
                    bs[s][c] = a;
                }
            }
            // context[c] = sum_{s<L} bs[s][c] * scale[s]
            float ctx[4] = {0.f, 0.f, 0.f, 0.f};
            #pragma unroll
            for (int s = 0; s < 4; s++) {
                float m = (s < L) ? x[s * 5] : 0.f;
                #pragma unroll
                for (int c = 0; c < 4; c++) ctx[c] += bs[s][c] * m;
            }
            // ys[m] = sum_c context[c] * Wreg[m][c]
            float ys[4];
            #pragma unroll
            for (int m = 0; m < 4; m++) {
                float a = 0.f;
                #pragma unroll
                for (int c = 0; c < 4; c++) a += ctx[c] * wr[m * 4 + c];
                ys[m] = a;
            }
            // projs[s] = sum_m bs[s][m] * ys[m], compacted for s < L
            #pragma unroll
            for (int s = 0; s < 4; s++) {
                if (s < L) {
                    float a = 0.f;
                    #pragma unroll
                    for (int m = 0; m < 4; m++) a += bs[s][m] * ys[m];
                    out[o + s] = a;
                }
            }
            o += (unsigned)L;
        }
    }
}

extern "C" void kernel_launch(void* const* d_in, const int* in_sizes, int n_in,
                              void* d_out, int out_size, void* d_ws, size_t ws_size,
                              hipStream_t stream) {
    const float* xss  = (const float*)d_in[0];
    const int*   seq  = (const int*)d_in[1];
    const float* Wcob = (const float*)d_in[2];
    const float* Wreg = (const float*)d_in[3];
    float* out = (float*)d_out;

    int n  = in_sizes[1];                       // B = 2,000,000
    int nb = (n + BLK_ELEMS - 1) / BLK_ELEMS;   // 1954 blocks

    unsigned* blockTotal = (unsigned*)d_ws;     // nb words; fully overwritten by K1

    tile_sum_kernel<<<nb, NT, 0, stream>>>(seq, blockTotal, n);
    main_kernel<<<nb, NT, 0, stream>>>(xss, seq, Wcob, Wreg, blockTotal, out, n);
}

// Round 5
// 241.929 us; speedup vs baseline: 1.2228x; 1.1218x over previous
//
#include <hip/hip_runtime.h>

#define NT 256
#define EPT 4                 // elements per thread (consecutive)
#define BLK_ELEMS (NT * EPT)  // 1024 elements per block

// K1: per-block (1024-element) sum of seq_lengths.
__global__ __launch_bounds__(NT) void tile_sum_kernel(const int* __restrict__ seq,
                                                      unsigned* __restrict__ blockTotal,
                                                      int n) {
    __shared__ unsigned wsum[4];
    const int tid = threadIdx.x, lane = tid & 63, wave = tid >> 6;
    const int base = blockIdx.x * BLK_ELEMS + tid * EPT;
    unsigned v = 0;
    if (base + EPT <= n) {
        int4 q = *(const int4*)(seq + base);
        v = (unsigned)(q.x + q.y + q.z + q.w);
    } else {
        for (int e = 0; e < EPT; e++)
            if (base + e < n) v += (unsigned)seq[base + e];
    }
    #pragma unroll
    for (int off = 32; off > 0; off >>= 1) v += __shfl_down(v, off);
    if (lane == 0) wsum[wave] = v;
    __syncthreads();
    if (tid == 0) blockTotal[blockIdx.x] = wsum[0] + wsum[1] + wsum[2] + wsum[3];
}

// K2: redundant global prefix over blockTotal (L2-broadcast), block scan,
// batched 320B/thread register load (max MLP), compute, LDS-staged
// compaction, coalesced stride-1 output copy.
__global__ __launch_bounds__(NT) void main_kernel(const float* __restrict__ xss,
                                                  const int* __restrict__ seq,
                                                  const float* __restrict__ Wcob,
                                                  const float* __restrict__ Wreg,
                                                  const unsigned* __restrict__ blockTotal,
                                                  float* __restrict__ out,
                                                  int n) {
    __shared__ unsigned wred[4];          // cross-wave partials, prefix reduce
    __shared__ unsigned wtot[4];          // cross-wave totals, block scan
    __shared__ float outbuf[BLK_ELEMS * 4];  // 16 KB: compacted block output

    const int tid = threadIdx.x, lane = tid & 63, wave = tid >> 6;
    const int bid = blockIdx.x;
    const int base = bid * BLK_ELEMS + tid * EPT;

    // ---- seq values (int4 when fully in-range) ----
    int l[EPT];
    if (base + EPT <= n) {
        int4 q = *(const int4*)(seq + base);
        l[0] = q.x; l[1] = q.y; l[2] = q.z; l[3] = q.w;
    } else {
        #pragma unroll
        for (int e = 0; e < EPT; e++) l[e] = (base + e < n) ? seq[base + e] : 0;
    }
    const unsigned tsum = (unsigned)(l[0] + l[1] + l[2] + l[3]);

    // ---- issue ALL 20 float4 xss loads NOW (contiguous 320B span/thread).
    //      They stay in flight under the scan below: max memory parallelism.
    const int cbase = (base + EPT <= n) ? base : (n - EPT);  // n >= EPT
    const float4* px = (const float4*)(xss + (size_t)cbase * 20);
    float4 q[20];
    #pragma unroll
    for (int i = 0; i < 20; i++) q[i] = px[i];

    // ---- global prefix: reduce blockTotal[0..bid) (<=8 strided L2 loads) ----
    unsigned acc = 0;
    for (int i = tid; i < bid; i += NT) acc += blockTotal[i];
    unsigned r = acc;
    #pragma unroll
    for (int off = 32; off > 0; off >>= 1) r += __shfl_down(r, off);
    if (lane == 0) wred[wave] = r;

    // ---- block-wide exclusive scan over thread sums ----
    unsigned v = tsum;
    #pragma unroll
    for (int off = 1; off < 64; off <<= 1) {
        unsigned t = __shfl_up(v, off);
        if (lane >= off) v += t;
    }
    if (lane == 63) wtot[wave] = v;
    __syncthreads();
    const unsigned prefix = wred[0] + wred[1] + wred[2] + wred[3];
    const unsigned total  = wtot[0] + wtot[1] + wtot[2] + wtot[3];
    unsigned woff = 0;
    #pragma unroll
    for (int w = 0; w < 4; w++) woff += (w < wave) ? wtot[w] : 0u;
    unsigned lo = woff + (v - tsum);      // block-local output slot

    // ---- uniform-address weight loads (scalarized by compiler) ----
    float wc[16], wr[16];
    #pragma unroll
    for (int i = 0; i < 16; i++) { wc[i] = Wcob[i]; wr[i] = Wreg[i]; }

    const float* x = (const float*)q;     // x[e*20 .. e*20+19] per element

    #pragma unroll
    for (int e = 0; e < EPT; e++) {
        const int L = l[e];               // 0 only for tail-padding elements
        const float* xe = x + e * 20;

        // bs[s][c] = sum_f fs[s][f] * Wcob[c][f]
        float bs[4][4];
        #pragma unroll
        for (int s = 0; s < 4; s++) {
            #pragma unroll
            for (int c = 0; c < 4; c++) {
                float a = 0.f;
                #pragma unroll
                for (int f = 0; f < 4; f++) a += xe[s * 5 + 1 + f] * wc[c * 4 + f];
                bs[s][c] = a;
            }
        }
        // context[c] = sum_{s<L} bs[s][c] * scale[s]
        float ctx[4] = {0.f, 0.f, 0.f, 0.f};
        #pragma unroll
        for (int s = 0; s < 4; s++) {
            float m = (s < L) ? xe[s * 5] : 0.f;
            #pragma unroll
            for (int c = 0; c < 4; c++) ctx[c] += bs[s][c] * m;
        }
        // ys[m] = sum_c context[c] * Wreg[m][c]
        float ys[4];
        #pragma unroll
        for (int m = 0; m < 4; m++) {
            float a = 0.f;
            #pragma unroll
            for (int c = 0; c < 4; c++) a += ctx[c] * wr[m * 4 + c];
            ys[m] = a;
        }
        // projs[s] = sum_m bs[s][m] * ys[m] -> stage compacted in LDS
        #pragma unroll
        for (int s = 0; s < 4; s++) {
            if (s < L) {
                float a = 0.f;
                #pragma unroll
                for (int m = 0; m < 4; m++) a += bs[s][m] * ys[m];
                outbuf[lo + s] = a;
            }
        }
        lo += (unsigned)((L > 0) ? L : 0);
    }

    // ---- coalesced stride-1 output copy: full 64B lines, no amplification ----
    __syncthreads();
    for (unsigned i = tid; i < total; i += NT)
        out[prefix + i] = outbuf[i];
}

extern "C" void kernel_launch(void* const* d_in, const int* in_sizes, int n_in,
                              void* d_out, int out_size, void* d_ws, size_t ws_size,
                              hipStream_t stream) {
    const float* xss  = (const float*)d_in[0];
    const int*   seq  = (const int*)d_in[1];
    const float* Wcob = (const float*)d_in[2];
    const float* Wreg = (const float*)d_in[3];
    float* out = (float*)d_out;

    int n  = in_sizes[1];                       // B = 2,000,000
    int nb = (n + BLK_ELEMS - 1) / BLK_ELEMS;   // 1954 blocks

    unsigned* blockTotal = (unsigned*)d_ws;     // nb words; fully overwritten by K1

    tile_sum_kernel<<<nb, NT, 0, stream>>>(seq, blockTotal, n);
    main_kernel<<<nb, NT, 0, stream>>>(xss, seq, Wcob, Wreg, blockTotal, out, n);
}